// Round 2
// baseline (1621.825 us; speedup 1.0000x reference)
//
#include <hip/hip_runtime.h>

#define N_NODES 50000
#define N_EDGES 800000
#define DIM 128

// ---------------- degree / dinv ----------------

__global__ __launch_bounds__(256) void deg_kernel(const int* __restrict__ edge_index,
                                                  float* __restrict__ deg) {
    int e = blockIdx.x * blockDim.x + threadIdx.x;
    if (e < N_EDGES) {
        int d = edge_index[N_EDGES + e];
        atomicAdd(&deg[d], 1.0f);
    }
}

__global__ __launch_bounds__(256) void dinv_kernel(float* __restrict__ deg) {
    int i = blockIdx.x * blockDim.x + threadIdx.x;
    if (i < N_NODES) deg[i] = rsqrtf(deg[i] + 1.0f);
}

// ---------------- GEMM: H = X @ W  (X:[N,128], W:[128,128]) ----------------
// W cached in LDS (64 KB). 256 threads = 128 cols x 2 rows. 16 rows/block.

#define ROWS_PER_BLOCK 16

__global__ __launch_bounds__(256) void gemm_kernel(const float* __restrict__ X,
                                                   const float* __restrict__ W,
                                                   float* __restrict__ H) {
    __shared__ float sW[DIM * DIM];
    int t = threadIdx.x;
    const float4* W4 = (const float4*)W;
    float4* sW4 = (float4*)sW;
#pragma unroll
    for (int i = 0; i < 16; ++i) sW4[i * 256 + t] = W4[i * 256 + t];
    __syncthreads();

    int tx = t & 127;  // output column
    int ty = t >> 7;   // row within pair
    int row0 = blockIdx.x * ROWS_PER_BLOCK;

    for (int rr = ty; rr < ROWS_PER_BLOCK; rr += 2) {
        int r = row0 + rr;
        if (r >= N_NODES) break;
        const float* xr = X + (size_t)r * DIM;
        float acc = 0.f;
#pragma unroll
        for (int k = 0; k < DIM; ++k) acc += xr[k] * sW[k * DIM + tx];
        H[(size_t)r * DIM + tx] = acc;
    }
}

// ---------------- edge scatter: AGG[dst] += H[src] * dinv[src]*dinv[dst] ----------------
// one wave64 per edge; lane handles a float2 (2 atomics)

__global__ __launch_bounds__(256) void scatter_kernel(const int* __restrict__ edge_index,
                                                      const float* __restrict__ dinv,
                                                      const float* __restrict__ H,
                                                      float* __restrict__ AGG) {
    int wave = (int)((blockIdx.x * (size_t)blockDim.x + threadIdx.x) >> 6);
    int lane = threadIdx.x & 63;
    if (wave >= N_EDGES) return;
    int s = edge_index[wave];
    int d = edge_index[N_EDGES + wave];
    float norm = dinv[s] * dinv[d];
    const float2* hs = (const float2*)(H + (size_t)s * DIM);
    float2 v = hs[lane];
    float* ag = AGG + (size_t)d * DIM;
    atomicAdd(&ag[2 * lane], v.x * norm);
    atomicAdd(&ag[2 * lane + 1], v.y * norm);
}

// ---------------- epilogues ----------------

__global__ __launch_bounds__(256) void finish1_kernel(const float* __restrict__ AGG,
                                                      const float* __restrict__ H,
                                                      const float* __restrict__ dinv,
                                                      const float* __restrict__ b,
                                                      float* __restrict__ OUT) {
    int i = blockIdx.x * blockDim.x + threadIdx.x;
    if (i >= N_NODES * DIM) return;
    int node = i >> 7;
    int col = i & 127;
    float di = dinv[node];
    float v = AGG[i] + H[i] * di * di + b[col];
    OUT[i] = fmaxf(v, 0.f);
}

__global__ __launch_bounds__(256) void finish2_kernel(const float* __restrict__ AGG,
                                                      const float* __restrict__ H,
                                                      const float* __restrict__ dinv,
                                                      const float* __restrict__ b,
                                                      const float* __restrict__ X,
                                                      float* __restrict__ OUT) {
    int i = blockIdx.x * blockDim.x + threadIdx.x;
    if (i >= N_NODES * DIM) return;
    int node = i >> 7;
    int col = i & 127;
    float di = dinv[node];
    float v = AGG[i] + H[i] * di * di + b[col] + X[i];
    OUT[i] = fmaxf(v, 0.f);
}

// ---------------- launch ----------------

extern "C" void kernel_launch(void* const* d_in, const int* in_sizes, int n_in,
                              void* d_out, int out_size, void* d_ws, size_t ws_size,
                              hipStream_t stream) {
    const float* x = (const float*)d_in[0];
    const int* edge_index = (const int*)d_in[1];   // harness passes integer inputs as int32
    const float* W1 = (const float*)d_in[2];
    const float* b1 = (const float*)d_in[3];
    const float* W2 = (const float*)d_in[4];
    const float* b2 = (const float*)d_in[5];
    float* out = (float*)d_out;

    char* ws = (char*)d_ws;
    float* dinv = (float*)ws;                    // 50000 floats (200 KB)
    float* agg  = (float*)(ws + (1 << 20));      // 50000*128 floats = 25.6 MB

    const size_t feat_bytes = (size_t)N_NODES * DIM * sizeof(float);

    // normalization (shared by both convs)
    hipMemsetAsync(dinv, 0, N_NODES * sizeof(float), stream);
    deg_kernel<<<(N_EDGES + 255) / 256, 256, 0, stream>>>(edge_index, dinv);
    dinv_kernel<<<(N_NODES + 255) / 256, 256, 0, stream>>>(dinv);

    // ---- conv1: h1 = x@W1 (into d_out), agg = scatter, out1 = relu(...) (into agg, in place)
    gemm_kernel<<<(N_NODES + ROWS_PER_BLOCK - 1) / ROWS_PER_BLOCK, 256, 0, stream>>>(x, W1, out);
    hipMemsetAsync(agg, 0, feat_bytes, stream);
    scatter_kernel<<<(N_EDGES * 64) / 256, 256, 0, stream>>>(edge_index, dinv, out, agg);
    finish1_kernel<<<(N_NODES * DIM + 255) / 256, 256, 0, stream>>>(agg, out, dinv, b1, agg);

    // ---- conv2: h2 = out1@W2 (into d_out, overwrites h1)
    gemm_kernel<<<(N_NODES + ROWS_PER_BLOCK - 1) / ROWS_PER_BLOCK, 256, 0, stream>>>(agg, W2, out);
    hipMemsetAsync(agg, 0, feat_bytes, stream);
    scatter_kernel<<<(N_EDGES * 64) / 256, 256, 0, stream>>>(edge_index, dinv, out, agg);
    finish2_kernel<<<(N_NODES * DIM + 255) / 256, 256, 0, stream>>>(agg, out, dinv, b2, x, out);
}

// Round 3
// 308.588 us; speedup vs baseline: 5.2556x; 5.2556x over previous
//
#include <hip/hip_runtime.h>

#define N_NODES 50000
#define N_EDGES 800000
#define DIM 128
#define NBLK 196  // ceil(50000/256)

// ---------------- degree histogram (int) ----------------

__global__ __launch_bounds__(256) void hist_kernel(const int* __restrict__ ei,
                                                   int* __restrict__ cnt) {
    int e = blockIdx.x * blockDim.x + threadIdx.x;
    if (e < N_EDGES) atomicAdd(&cnt[ei[N_EDGES + e]], 1);
}

__global__ __launch_bounds__(256) void dinv_kernel(const int* __restrict__ cnt,
                                                   float* __restrict__ dinv) {
    int i = blockIdx.x * blockDim.x + threadIdx.x;
    if (i < N_NODES) dinv[i] = rsqrtf((float)cnt[i] + 1.0f);
}

// ---------------- 2-level exclusive scan -> rowptr, cursor ----------------

__global__ __launch_bounds__(256) void scanA_kernel(const int* __restrict__ cnt,
                                                    int* __restrict__ bsum) {
    __shared__ int sd[256];
    int t = threadIdx.x;
    int i = blockIdx.x * 256 + t;
    sd[t] = (i < N_NODES) ? cnt[i] : 0;
    __syncthreads();
    for (int off = 128; off > 0; off >>= 1) {
        if (t < off) sd[t] += sd[t + off];
        __syncthreads();
    }
    if (t == 0) bsum[blockIdx.x] = sd[0];
}

__global__ __launch_bounds__(256) void scanB_kernel(const int* __restrict__ bsum,
                                                    int* __restrict__ boff) {
    __shared__ int sd[256];
    int t = threadIdx.x;
    int v0 = (t < NBLK) ? bsum[t] : 0;
    sd[t] = v0;
    __syncthreads();
    for (int off = 1; off < 256; off <<= 1) {
        int v = (t >= off) ? sd[t - off] : 0;
        __syncthreads();
        sd[t] += v;
        __syncthreads();
    }
    if (t < NBLK) boff[t] = sd[t] - v0;  // exclusive
}

__global__ __launch_bounds__(256) void scanC_kernel(const int* __restrict__ cnt,
                                                    const int* __restrict__ boff,
                                                    int* __restrict__ rowptr,
                                                    int* __restrict__ cursor) {
    __shared__ int sd[256];
    int t = threadIdx.x;
    int i = blockIdx.x * 256 + t;
    int v = (i < N_NODES) ? cnt[i] : 0;
    sd[t] = v;
    __syncthreads();
    for (int off = 1; off < 256; off <<= 1) {
        int u = (t >= off) ? sd[t - off] : 0;
        __syncthreads();
        sd[t] += u;
        __syncthreads();
    }
    int excl = sd[t] - v + boff[blockIdx.x];
    if (i < N_NODES) { rowptr[i] = excl; cursor[i] = excl; }
    if (i == N_NODES) rowptr[N_NODES] = N_EDGES;
}

__global__ __launch_bounds__(256) void fill_kernel(const int* __restrict__ ei,
                                                   int* __restrict__ cursor,
                                                   int* __restrict__ csr_src) {
    int e = blockIdx.x * blockDim.x + threadIdx.x;
    if (e < N_EDGES) {
        int s = ei[e];
        int d = ei[N_EDGES + e];
        int p = atomicAdd(&cursor[d], 1);
        csr_src[p] = s;
    }
}

// ---------------- GEMM: Hs = (X @ W) * dinv[row]  ----------------
// 256 threads: tx=t&31 (4 cols each), ty=t>>5 (4 rows each) -> 32 rows x 128 cols/block

#define GR 32

__global__ __launch_bounds__(256) void gemm_kernel(const float* __restrict__ X,
                                                   const float* __restrict__ W,
                                                   const float* __restrict__ dinv,
                                                   float* __restrict__ Hs) {
    __shared__ float4 sW[DIM * 32];  // sW[k][c4], 64 KB
    int t = threadIdx.x;
    const float4* W4 = (const float4*)W;
#pragma unroll
    for (int i = 0; i < 16; ++i) sW[i * 256 + t] = W4[i * 256 + t];
    __syncthreads();

    int tx = t & 31;
    int ty = t >> 5;
    int r0 = blockIdx.x * GR + ty * 4;
    if (r0 >= N_NODES) return;  // N%4==0 -> 4-row group fully in or out

    const float* x0 = X + (size_t)r0 * DIM;
    float4 acc[4];
#pragma unroll
    for (int i = 0; i < 4; ++i) acc[i] = make_float4(0.f, 0.f, 0.f, 0.f);

    for (int k4 = 0; k4 < 32; ++k4) {
        float4 xv[4];
#pragma unroll
        for (int i = 0; i < 4; ++i)
            xv[i] = *(const float4*)(x0 + i * DIM + k4 * 4);
#pragma unroll
        for (int kk = 0; kk < 4; ++kk) {
            float4 w = sW[(k4 * 4 + kk) * 32 + tx];
#pragma unroll
            for (int i = 0; i < 4; ++i) {
                float xs = (kk == 0) ? xv[i].x : (kk == 1) ? xv[i].y : (kk == 2) ? xv[i].z : xv[i].w;
                acc[i].x += xs * w.x;
                acc[i].y += xs * w.y;
                acc[i].z += xs * w.z;
                acc[i].w += xs * w.w;
            }
        }
    }
#pragma unroll
    for (int i = 0; i < 4; ++i) {
        float di = dinv[r0 + i];
        float4 o = acc[i];
        o.x *= di; o.y *= di; o.z *= di; o.w *= di;
        *(float4*)(Hs + (size_t)(r0 + i) * DIM + tx * 4) = o;
    }
}

// ---------------- aggregation (gather): one wave per dst node ----------------
// out[d] = relu( dinv[d] * (sum_{s in N(d)} Hs[s] + Hs[d]) + b [+ resid] )

template <bool RES>
__global__ __launch_bounds__(256) void agg_kernel(const int* __restrict__ rowptr,
                                                  const int* __restrict__ csr_src,
                                                  const float* __restrict__ Hs,
                                                  const float* __restrict__ dinv,
                                                  const float* __restrict__ b,
                                                  const float* __restrict__ resid,
                                                  float* __restrict__ out) {
    int node = (int)((blockIdx.x * (size_t)blockDim.x + threadIdx.x) >> 6);
    int lane = threadIdx.x & 63;
    if (node >= N_NODES) return;

    int beg = rowptr[node];
    int end = rowptr[node + 1];
    const float2* H2 = (const float2*)Hs;
    float2 acc = H2[(size_t)node * 64 + lane];  // self contribution

    int e = beg;
    for (; e + 1 < end; e += 2) {
        int s0 = csr_src[e];
        int s1 = csr_src[e + 1];
        float2 v0 = H2[(size_t)s0 * 64 + lane];
        float2 v1 = H2[(size_t)s1 * 64 + lane];
        acc.x += v0.x + v1.x;
        acc.y += v0.y + v1.y;
    }
    if (e < end) {
        int s = csr_src[e];
        float2 v = H2[(size_t)s * 64 + lane];
        acc.x += v.x;
        acc.y += v.y;
    }

    float di = dinv[node];
    float2 bb = ((const float2*)b)[lane];
    float ox = acc.x * di + bb.x;
    float oy = acc.y * di + bb.y;
    if (RES) {
        float2 rv = ((const float2*)resid)[(size_t)node * 64 + lane];
        ox += rv.x;
        oy += rv.y;
    }
    ((float2*)out)[(size_t)node * 64 + lane] = make_float2(fmaxf(ox, 0.f), fmaxf(oy, 0.f));
}

// ---------------- launch ----------------

extern "C" void kernel_launch(void* const* d_in, const int* in_sizes, int n_in,
                              void* d_out, int out_size, void* d_ws, size_t ws_size,
                              hipStream_t stream) {
    const float* x = (const float*)d_in[0];
    const int* edge_index = (const int*)d_in[1];
    const float* W1 = (const float*)d_in[2];
    const float* b1 = (const float*)d_in[3];
    const float* W2 = (const float*)d_in[4];
    const float* b2 = (const float*)d_in[5];
    float* out = (float*)d_out;

    char* ws = (char*)d_ws;
    int*   cnt     = (int*)(ws + 0);              // 200 KB
    int*   rowptr  = (int*)(ws + (256 << 10));    // 200 KB + 4
    int*   cursor  = (int*)(ws + (512 << 10));    // 200 KB
    int*   bsum    = (int*)(ws + (768 << 10));    // 784 B
    int*   boff    = (int*)(ws + (772 << 10));    // 784 B
    float* dinv    = (float*)(ws + (1 << 20));    // 200 KB
    int*   csr_src = (int*)(ws + (2 << 20));      // 3.2 MB
    float* Hs      = (float*)(ws + (8 << 20));    // 25.6 MB

    // ---- CSR build + normalization
    hipMemsetAsync(cnt, 0, N_NODES * sizeof(int), stream);
    hist_kernel<<<(N_EDGES + 255) / 256, 256, 0, stream>>>(edge_index, cnt);
    dinv_kernel<<<NBLK, 256, 0, stream>>>(cnt, dinv);
    scanA_kernel<<<NBLK, 256, 0, stream>>>(cnt, bsum);
    scanB_kernel<<<1, 256, 0, stream>>>(bsum, boff);
    scanC_kernel<<<NBLK, 256, 0, stream>>>(cnt, boff, rowptr, cursor);
    fill_kernel<<<(N_EDGES + 255) / 256, 256, 0, stream>>>(edge_index, cursor, csr_src);

    const int gemm_grid = (N_NODES + GR - 1) / GR;
    const int agg_grid = (N_NODES * 64 + 255) / 256;

    // ---- conv1: Hs = (x@W1)*dinv ; out1 = relu(agg + b1) -> d_out
    gemm_kernel<<<gemm_grid, 256, 0, stream>>>(x, W1, dinv, Hs);
    agg_kernel<false><<<agg_grid, 256, 0, stream>>>(rowptr, csr_src, Hs, dinv, b1, nullptr, out);

    // ---- conv2: Hs = (out1@W2)*dinv ; out = relu(agg + b2 + x) -> d_out
    gemm_kernel<<<gemm_grid, 256, 0, stream>>>(out, W2, dinv, Hs);
    agg_kernel<true><<<agg_grid, 256, 0, stream>>>(rowptr, csr_src, Hs, dinv, b2, x, out);
}

// Round 4
// 258.162 us; speedup vs baseline: 6.2822x; 1.1953x over previous
//
#include <hip/hip_runtime.h>

#define N_NODES 50000
#define N_EDGES 800000
#define DIM 128
#define NBLK 196  // ceil(50000/256)

typedef unsigned int uint;

// ---- bf16 pack/unpack helpers (round-to-nearest-even) ----
__device__ __forceinline__ uint f2bf(float f) {
    uint u = __float_as_uint(f);
    return (u + 0x7FFFu + ((u >> 16) & 1u)) >> 16;
}
__device__ __forceinline__ float2 bf2f2(uint u) {
    return make_float2(__uint_as_float(u << 16), __uint_as_float(u & 0xFFFF0000u));
}

// ---------------- degree histogram (int) ----------------

__global__ __launch_bounds__(256) void hist_kernel(const int* __restrict__ ei,
                                                   int* __restrict__ cnt) {
    int e = blockIdx.x * blockDim.x + threadIdx.x;
    if (e < N_EDGES) atomicAdd(&cnt[ei[N_EDGES + e]], 1);
}

// ---------------- 2-level exclusive scan -> rowptr, cursor, dinv ----------------

__global__ __launch_bounds__(256) void scanA_kernel(const int* __restrict__ cnt,
                                                    int* __restrict__ bsum) {
    __shared__ int sd[256];
    int t = threadIdx.x;
    int i = blockIdx.x * 256 + t;
    sd[t] = (i < N_NODES) ? cnt[i] : 0;
    __syncthreads();
    for (int off = 128; off > 0; off >>= 1) {
        if (t < off) sd[t] += sd[t + off];
        __syncthreads();
    }
    if (t == 0) bsum[blockIdx.x] = sd[0];
}

__global__ __launch_bounds__(256) void scanB_kernel(const int* __restrict__ bsum,
                                                    int* __restrict__ boff) {
    __shared__ int sd[256];
    int t = threadIdx.x;
    int v0 = (t < NBLK) ? bsum[t] : 0;
    sd[t] = v0;
    __syncthreads();
    for (int off = 1; off < 256; off <<= 1) {
        int v = (t >= off) ? sd[t - off] : 0;
        __syncthreads();
        sd[t] += v;
        __syncthreads();
    }
    if (t < NBLK) boff[t] = sd[t] - v0;  // exclusive
}

__global__ __launch_bounds__(256) void scanC_kernel(const int* __restrict__ cnt,
                                                    const int* __restrict__ boff,
                                                    int* __restrict__ rowptr,
                                                    int* __restrict__ cursor,
                                                    float* __restrict__ dinv) {
    __shared__ int sd[256];
    int t = threadIdx.x;
    int i = blockIdx.x * 256 + t;
    int v = (i < N_NODES) ? cnt[i] : 0;
    sd[t] = v;
    __syncthreads();
    for (int off = 1; off < 256; off <<= 1) {
        int u = (t >= off) ? sd[t - off] : 0;
        __syncthreads();
        sd[t] += u;
        __syncthreads();
    }
    int excl = sd[t] - v + boff[blockIdx.x];
    if (i < N_NODES) {
        rowptr[i] = excl;
        cursor[i] = excl;
        dinv[i] = rsqrtf((float)v + 1.0f);
    }
    if (i == N_NODES) rowptr[N_NODES] = N_EDGES;
}

__global__ __launch_bounds__(256) void fill_kernel(const int* __restrict__ ei,
                                                   int* __restrict__ cursor,
                                                   int* __restrict__ csr_src) {
    int e = blockIdx.x * blockDim.x + threadIdx.x;
    if (e < N_EDGES) {
        int s = ei[e];
        int d = ei[N_EDGES + e];
        int p = atomicAdd(&cursor[d], 1);
        csr_src[p] = s;
    }
}

// ---------------- GEMM: Hs = bf16( (X @ W) * dinv[row] ) ----------------
// 256 threads: tx=t&31 (4 cols each), ty=t>>5 (4 rows each) -> 32 rows x 128 cols/block

#define GR 32

__global__ __launch_bounds__(256) void gemm_kernel(const float* __restrict__ X,
                                                   const float* __restrict__ W,
                                                   const float* __restrict__ dinv,
                                                   uint* __restrict__ Hs) {
    __shared__ float4 sW[DIM * 32];  // sW[k][c4], 64 KB
    int t = threadIdx.x;
    const float4* W4 = (const float4*)W;
#pragma unroll
    for (int i = 0; i < 16; ++i) sW[i * 256 + t] = W4[i * 256 + t];
    __syncthreads();

    int tx = t & 31;
    int ty = t >> 5;
    int r0 = blockIdx.x * GR + ty * 4;
    if (r0 >= N_NODES) return;  // N%4==0 -> 4-row group fully in or out

    const float* x0 = X + (size_t)r0 * DIM;
    float4 acc[4];
#pragma unroll
    for (int i = 0; i < 4; ++i) acc[i] = make_float4(0.f, 0.f, 0.f, 0.f);

    for (int k4 = 0; k4 < 32; ++k4) {
        float4 xv[4];
#pragma unroll
        for (int i = 0; i < 4; ++i)
            xv[i] = *(const float4*)(x0 + i * DIM + k4 * 4);
#pragma unroll
        for (int kk = 0; kk < 4; ++kk) {
            float4 w = sW[(k4 * 4 + kk) * 32 + tx];
#pragma unroll
            for (int i = 0; i < 4; ++i) {
                float xs = (kk == 0) ? xv[i].x : (kk == 1) ? xv[i].y : (kk == 2) ? xv[i].z : xv[i].w;
                acc[i].x += xs * w.x;
                acc[i].y += xs * w.y;
                acc[i].z += xs * w.z;
                acc[i].w += xs * w.w;
            }
        }
    }
#pragma unroll
    for (int i = 0; i < 4; ++i) {
        float di = dinv[r0 + i];
        uint lo = f2bf(acc[i].x * di) | (f2bf(acc[i].y * di) << 16);
        uint hi = f2bf(acc[i].z * di) | (f2bf(acc[i].w * di) << 16);
        // row stride = 128 bf16 = 64 uints; thread writes uint2 at index tx
        ((uint2*)(Hs + (size_t)(r0 + i) * 64))[tx] = make_uint2(lo, hi);
    }
}

// ---------------- aggregation (gather): one wave per dst node ----------------
// out[d] = relu( dinv[d] * (sum_{s in N(d)} Hs[s] + Hs[d]) + b [+ resid] )

template <bool RES>
__global__ __launch_bounds__(256) void agg_kernel(const int* __restrict__ rowptr,
                                                  const int* __restrict__ csr_src,
                                                  const uint* __restrict__ Hs,
                                                  const float* __restrict__ dinv,
                                                  const float* __restrict__ b,
                                                  const float* __restrict__ resid,
                                                  float* __restrict__ out) {
    int node = (int)((blockIdx.x * (size_t)blockDim.x + threadIdx.x) >> 6);
    int lane = threadIdx.x & 63;
    if (node >= N_NODES) return;

    int beg = rowptr[node];
    int end = rowptr[node + 1];

    float2 self = bf2f2(Hs[(size_t)node * 64 + lane]);
    float ax = self.x, ay = self.y;

    int e = beg;
    for (; e + 3 < end; e += 4) {
        int s0 = csr_src[e], s1 = csr_src[e + 1], s2 = csr_src[e + 2], s3 = csr_src[e + 3];
        uint u0 = Hs[(size_t)s0 * 64 + lane];
        uint u1 = Hs[(size_t)s1 * 64 + lane];
        uint u2 = Hs[(size_t)s2 * 64 + lane];
        uint u3 = Hs[(size_t)s3 * 64 + lane];
        float2 v0 = bf2f2(u0), v1 = bf2f2(u1), v2 = bf2f2(u2), v3 = bf2f2(u3);
        ax += (v0.x + v1.x) + (v2.x + v3.x);
        ay += (v0.y + v1.y) + (v2.y + v3.y);
    }
    for (; e < end; ++e) {
        float2 v = bf2f2(Hs[(size_t)csr_src[e] * 64 + lane]);
        ax += v.x;
        ay += v.y;
    }

    float di = dinv[node];
    float2 bb = ((const float2*)b)[lane];
    float ox = ax * di + bb.x;
    float oy = ay * di + bb.y;
    if (RES) {
        float2 rv = ((const float2*)resid)[(size_t)node * 64 + lane];
        ox += rv.x;
        oy += rv.y;
    }
    ((float2*)out)[(size_t)node * 64 + lane] = make_float2(fmaxf(ox, 0.f), fmaxf(oy, 0.f));
}

// ---------------- launch ----------------

extern "C" void kernel_launch(void* const* d_in, const int* in_sizes, int n_in,
                              void* d_out, int out_size, void* d_ws, size_t ws_size,
                              hipStream_t stream) {
    const float* x = (const float*)d_in[0];
    const int* edge_index = (const int*)d_in[1];
    const float* W1 = (const float*)d_in[2];
    const float* b1 = (const float*)d_in[3];
    const float* W2 = (const float*)d_in[4];
    const float* b2 = (const float*)d_in[5];
    float* out = (float*)d_out;

    char* ws = (char*)d_ws;
    int*   cnt     = (int*)(ws + 0);              // 200 KB
    int*   rowptr  = (int*)(ws + (256 << 10));    // 200 KB + 4
    int*   cursor  = (int*)(ws + (512 << 10));    // 200 KB
    int*   bsum    = (int*)(ws + (768 << 10));    // 784 B
    int*   boff    = (int*)(ws + (772 << 10));    // 784 B
    float* dinv    = (float*)(ws + (1 << 20));    // 200 KB
    int*   csr_src = (int*)(ws + (2 << 20));      // 3.2 MB
    uint*  Hs      = (uint*)(ws + (8 << 20));     // 12.8 MB (bf16 packed)

    // ---- CSR build + normalization
    hipMemsetAsync(cnt, 0, N_NODES * sizeof(int), stream);
    hist_kernel<<<(N_EDGES + 255) / 256, 256, 0, stream>>>(edge_index, cnt);
    scanA_kernel<<<NBLK, 256, 0, stream>>>(cnt, bsum);
    scanB_kernel<<<1, 256, 0, stream>>>(bsum, boff);
    scanC_kernel<<<NBLK, 256, 0, stream>>>(cnt, boff, rowptr, cursor, dinv);
    fill_kernel<<<(N_EDGES + 255) / 256, 256, 0, stream>>>(edge_index, cursor, csr_src);

    const int gemm_grid = (N_NODES + GR - 1) / GR;
    const int agg_grid = (N_NODES * 64 + 255) / 256;

    // ---- conv1: Hs = bf16((x@W1)*dinv) ; out1 = relu(agg + b1) -> d_out
    gemm_kernel<<<gemm_grid, 256, 0, stream>>>(x, W1, dinv, Hs);
    agg_kernel<false><<<agg_grid, 256, 0, stream>>>(rowptr, csr_src, Hs, dinv, b1, nullptr, out);

    // ---- conv2: Hs = bf16((out1@W2)*dinv) ; out = relu(agg + b2 + x) -> d_out
    gemm_kernel<<<gemm_grid, 256, 0, stream>>>(out, W2, dinv, Hs);
    agg_kernel<true><<<agg_grid, 256, 0, stream>>>(rowptr, csr_src, Hs, dinv, b2, x, out);
}

// Round 5
// 185.543 us; speedup vs baseline: 8.7410x; 1.3914x over previous
//
#include <hip/hip_runtime.h>

#define N_NODES 50000
#define N_EDGES 800000
#define DIM 128
#define NB 391          // buckets of 128 nodes: (49999>>7)+1
#define CAP 2560        // padded capacity per bucket (mean 2048, +11 sigma)
#define BIN_CHUNK 4096  // edges per BIN block
#define BIN_BLOCKS 196  // ceil(800000/4096)

typedef unsigned int uint;

// ---- bf16 pack/unpack helpers (round-to-nearest-even) ----
__device__ __forceinline__ uint f2bf(float f) {
    uint u = __float_as_uint(f);
    return (u + 0x7FFFu + ((u >> 16) & 1u)) >> 16;
}
__device__ __forceinline__ float2 bf2f2(uint u) {
    return make_float2(__uint_as_float(u << 16), __uint_as_float(u & 0xFFFF0000u));
}

// ---------------- bucket cursor init ----------------

__global__ __launch_bounds__(256) void initcur_kernel(int* __restrict__ bincursor) {
    int b = blockIdx.x * blockDim.x + threadIdx.x;
    if (b < NB) bincursor[b] = b * CAP;
}

// ---------------- BIN: scatter edges into 391 dst-buckets ----------------
// per-block LDS histogram -> one global atomic per (block,bucket) -> LDS ranks

__global__ __launch_bounds__(256) void bin_kernel(const int* __restrict__ ei,
                                                  int* __restrict__ bincursor,
                                                  int2* __restrict__ pairs) {
    __shared__ int lh[NB];
    __shared__ int lbase[NB];
    int t = threadIdx.x;
    int eb = blockIdx.x * BIN_CHUNK;

    for (int b = t; b < NB; b += 256) lh[b] = 0;
    __syncthreads();

    int s_reg[16], d_reg[16];
#pragma unroll
    for (int i = 0; i < 16; ++i) {
        int e = eb + i * 256 + t;
        if (e < N_EDGES) {
            s_reg[i] = ei[e];
            d_reg[i] = ei[N_EDGES + e];
            atomicAdd(&lh[d_reg[i] >> 7], 1);
        } else {
            d_reg[i] = -1;
        }
    }
    __syncthreads();

    // reserve space per bucket
    for (int b = t; b < NB; b += 256) {
        int c = lh[b];
        lbase[b] = c ? atomicAdd(&bincursor[b], c) : 0;
    }
    __syncthreads();
    for (int b = t; b < NB; b += 256) lh[b] = 0;  // reuse as rank counters
    __syncthreads();

#pragma unroll
    for (int i = 0; i < 16; ++i) {
        int d = d_reg[i];
        if (d >= 0) {
            int bin = d >> 7;
            int r = atomicAdd(&lh[bin], 1);
            pairs[lbase[bin] + r] = make_int2(s_reg[i], d);
        }
    }
}

// ---------------- FILL2: per-bucket local CSR build ----------------
// block b owns nodes [b*128, b*128+128) and csr region [b*CAP, ...)

__global__ __launch_bounds__(256) void fill2_kernel(const int2* __restrict__ pairs,
                                                    const int* __restrict__ bincursor,
                                                    int* __restrict__ rowbeg,
                                                    int* __restrict__ rowend,
                                                    float* __restrict__ dinv,
                                                    int* __restrict__ csr_src) {
    __shared__ int deg[128];
    __shared__ int sc[128];
    __shared__ int cur[128];
    int t = threadIdx.x;
    int blk = blockIdx.x;
    int bs = blk * CAP;
    int be = bincursor[blk];  // final cursor = bs + count

    if (t < 128) deg[t] = 0;
    __syncthreads();

    for (int p = bs + t; p < be; p += 256) atomicAdd(&deg[pairs[p].y & 127], 1);
    __syncthreads();

    if (t < 128) sc[t] = deg[t];
    __syncthreads();
#pragma unroll
    for (int off = 1; off < 128; off <<= 1) {
        int v = (t < 128 && t >= off) ? sc[t - off] : 0;
        __syncthreads();
        if (t < 128) sc[t] += v;
        __syncthreads();
    }

    if (t < 128) {
        int ex = sc[t] - deg[t];
        cur[t] = ex;
        int node = blk * 128 + t;
        if (node < N_NODES) {
            rowbeg[node] = bs + ex;
            rowend[node] = bs + sc[t];
            dinv[node] = rsqrtf((float)deg[t] + 1.0f);
        }
    }
    __syncthreads();

    for (int p = bs + t; p < be; p += 256) {
        int2 sd = pairs[p];
        int r = atomicAdd(&cur[sd.y & 127], 1);
        csr_src[bs + r] = sd.x;
    }
}

// ---------------- GEMM: Hs = bf16( (X @ W) * dinv[row] ) ----------------

#define GR 32

__global__ __launch_bounds__(256) void gemm_kernel(const float* __restrict__ X,
                                                   const float* __restrict__ W,
                                                   const float* __restrict__ dinv,
                                                   uint* __restrict__ Hs) {
    __shared__ float4 sW[DIM * 32];  // sW[k][c4], 64 KB
    int t = threadIdx.x;
    const float4* W4 = (const float4*)W;
#pragma unroll
    for (int i = 0; i < 16; ++i) sW[i * 256 + t] = W4[i * 256 + t];
    __syncthreads();

    int tx = t & 31;
    int ty = t >> 5;
    int r0 = blockIdx.x * GR + ty * 4;
    if (r0 >= N_NODES) return;  // N%4==0

    const float* x0 = X + (size_t)r0 * DIM;
    float4 acc[4];
#pragma unroll
    for (int i = 0; i < 4; ++i) acc[i] = make_float4(0.f, 0.f, 0.f, 0.f);

    for (int k4 = 0; k4 < 32; ++k4) {
        float4 xv[4];
#pragma unroll
        for (int i = 0; i < 4; ++i)
            xv[i] = *(const float4*)(x0 + i * DIM + k4 * 4);
#pragma unroll
        for (int kk = 0; kk < 4; ++kk) {
            float4 w = sW[(k4 * 4 + kk) * 32 + tx];
#pragma unroll
            for (int i = 0; i < 4; ++i) {
                float xs = (kk == 0) ? xv[i].x : (kk == 1) ? xv[i].y : (kk == 2) ? xv[i].z : xv[i].w;
                acc[i].x += xs * w.x;
                acc[i].y += xs * w.y;
                acc[i].z += xs * w.z;
                acc[i].w += xs * w.w;
            }
        }
    }
#pragma unroll
    for (int i = 0; i < 4; ++i) {
        float di = dinv[r0 + i];
        uint lo = f2bf(acc[i].x * di) | (f2bf(acc[i].y * di) << 16);
        uint hi = f2bf(acc[i].z * di) | (f2bf(acc[i].w * di) << 16);
        ((uint2*)(Hs + (size_t)(r0 + i) * 64))[tx] = make_uint2(lo, hi);
    }
}

// ---------------- aggregation (gather): one wave per dst node ----------------

template <bool RES>
__global__ __launch_bounds__(256) void agg_kernel(const int* __restrict__ rowbeg,
                                                  const int* __restrict__ rowend,
                                                  const int* __restrict__ csr_src,
                                                  const uint* __restrict__ Hs,
                                                  const float* __restrict__ dinv,
                                                  const float* __restrict__ b,
                                                  const float* __restrict__ resid,
                                                  float* __restrict__ out) {
    int node = (int)((blockIdx.x * (size_t)blockDim.x + threadIdx.x) >> 6);
    int lane = threadIdx.x & 63;
    if (node >= N_NODES) return;

    int beg = rowbeg[node];
    int end = rowend[node];

    float2 self = bf2f2(Hs[(size_t)node * 64 + lane]);
    float ax = self.x, ay = self.y;

    int e = beg;
    for (; e + 3 < end; e += 4) {
        int s0 = csr_src[e], s1 = csr_src[e + 1], s2 = csr_src[e + 2], s3 = csr_src[e + 3];
        uint u0 = Hs[(size_t)s0 * 64 + lane];
        uint u1 = Hs[(size_t)s1 * 64 + lane];
        uint u2 = Hs[(size_t)s2 * 64 + lane];
        uint u3 = Hs[(size_t)s3 * 64 + lane];
        float2 v0 = bf2f2(u0), v1 = bf2f2(u1), v2 = bf2f2(u2), v3 = bf2f2(u3);
        ax += (v0.x + v1.x) + (v2.x + v3.x);
        ay += (v0.y + v1.y) + (v2.y + v3.y);
    }
    for (; e < end; ++e) {
        float2 v = bf2f2(Hs[(size_t)csr_src[e] * 64 + lane]);
        ax += v.x;
        ay += v.y;
    }

    float di = dinv[node];
    float2 bb = ((const float2*)b)[lane];
    float ox = ax * di + bb.x;
    float oy = ay * di + bb.y;
    if (RES) {
        float2 rv = ((const float2*)resid)[(size_t)node * 64 + lane];
        ox += rv.x;
        oy += rv.y;
    }
    ((float2*)out)[(size_t)node * 64 + lane] = make_float2(fmaxf(ox, 0.f), fmaxf(oy, 0.f));
}

// ---------------- launch ----------------

extern "C" void kernel_launch(void* const* d_in, const int* in_sizes, int n_in,
                              void* d_out, int out_size, void* d_ws, size_t ws_size,
                              hipStream_t stream) {
    const float* x = (const float*)d_in[0];
    const int* edge_index = (const int*)d_in[1];
    const float* W1 = (const float*)d_in[2];
    const float* b1 = (const float*)d_in[3];
    const float* W2 = (const float*)d_in[4];
    const float* b2 = (const float*)d_in[5];
    float* out = (float*)d_out;

    char* ws = (char*)d_ws;
    int*   bincursor = (int*)(ws + 0);             // 391 ints
    float* dinv      = (float*)(ws + (64 << 10));  // 200 KB
    int*   rowbeg    = (int*)(ws + (320 << 10));   // 200 KB
    int*   rowend    = (int*)(ws + (576 << 10));   // 200 KB
    int*   csr_src   = (int*)(ws + (1 << 20));     // padded: 391*2560*4 = 3.9 MB
    int2*  pairs     = (int2*)(ws + (6 << 20));    // padded: 391*2560*8 = 7.9 MB
    uint*  Hs        = (uint*)(ws + (15 << 20));   // 12.8 MB (bf16 packed)

    // ---- CSR build (bucketed, no per-edge global atomics)
    initcur_kernel<<<2, 256, 0, stream>>>(bincursor);
    bin_kernel<<<BIN_BLOCKS, 256, 0, stream>>>(edge_index, bincursor, pairs);
    fill2_kernel<<<NB, 256, 0, stream>>>(pairs, bincursor, rowbeg, rowend, dinv, csr_src);

    const int gemm_grid = (N_NODES + GR - 1) / GR;
    const int agg_grid = (N_NODES * 64 + 255) / 256;

    // ---- conv1: Hs = bf16((x@W1)*dinv) ; out1 = relu(agg + b1) -> d_out
    gemm_kernel<<<gemm_grid, 256, 0, stream>>>(x, W1, dinv, Hs);
    agg_kernel<false><<<agg_grid, 256, 0, stream>>>(rowbeg, rowend, csr_src, Hs, dinv, b1, nullptr, out);

    // ---- conv2: Hs = bf16((out1@W2)*dinv) ; out = relu(agg + b2 + x) -> d_out
    gemm_kernel<<<gemm_grid, 256, 0, stream>>>(out, W2, dinv, Hs);
    agg_kernel<true><<<agg_grid, 256, 0, stream>>>(rowbeg, rowend, csr_src, Hs, dinv, b2, x, out);
}

// Round 6
// 163.192 us; speedup vs baseline: 9.9381x; 1.1370x over previous
//
#include <hip/hip_runtime.h>

#define N_NODES 50000
#define N_EDGES 800000
#define DIM 128
#define NB 391          // buckets of 128 nodes
#define CAP 2560        // padded capacity per bucket (mean 2048)
#define BIN_CHUNK 4096
#define BIN_BLOCKS 196

typedef unsigned int uint;
typedef unsigned short ushort;
typedef __attribute__((ext_vector_type(8))) __bf16 bf16x8;
typedef __attribute__((ext_vector_type(4))) float f32x4;

// ---- bf16 pack/unpack helpers (round-to-nearest-even) ----
__device__ __forceinline__ uint f2bf(float f) {
    uint u = __float_as_uint(f);
    return (u + 0x7FFFu + ((u >> 16) & 1u)) >> 16;
}
__device__ __forceinline__ float2 bf2f2(uint u) {
    return make_float2(__uint_as_float(u << 16), __uint_as_float(u & 0xFFFF0000u));
}

// ---------------- bucket cursor init ----------------

__global__ __launch_bounds__(256) void initcur_kernel(int* __restrict__ bincursor) {
    int b = blockIdx.x * blockDim.x + threadIdx.x;
    if (b < NB) bincursor[b] = b * CAP;
}

// ---------------- W^T bf16 pre-pack: Wt[n][k2] = pack(W[2k2][n], W[2k2+1][n]) ----------------

__global__ __launch_bounds__(256) void wt_kernel(const float* __restrict__ W1,
                                                 const float* __restrict__ W2,
                                                 uint* __restrict__ Wt1,
                                                 uint* __restrict__ Wt2) {
    int idx = blockIdx.x * 256 + threadIdx.x;  // 0..16383
    const float* W = (idx < 8192) ? W1 : W2;
    uint* Wt = (idx < 8192) ? Wt1 : Wt2;
    int i = idx & 8191;
    int n = i >> 6, k2 = i & 63;
    uint lo = f2bf(W[(2 * k2) * DIM + n]);
    uint hi = f2bf(W[(2 * k2 + 1) * DIM + n]);
    Wt[i] = lo | (hi << 16);
}

// ---------------- BIN: scatter edges into 391 dst-buckets ----------------

__global__ __launch_bounds__(256) void bin_kernel(const int* __restrict__ ei,
                                                  int* __restrict__ bincursor,
                                                  int2* __restrict__ pairs) {
    __shared__ int lh[NB];
    __shared__ int lbase[NB];
    int t = threadIdx.x;
    int eb = blockIdx.x * BIN_CHUNK;

    for (int b = t; b < NB; b += 256) lh[b] = 0;
    __syncthreads();

    int s_reg[16], d_reg[16];
#pragma unroll
    for (int i = 0; i < 16; ++i) {
        int e = eb + i * 256 + t;
        if (e < N_EDGES) {
            s_reg[i] = ei[e];
            d_reg[i] = ei[N_EDGES + e];
            atomicAdd(&lh[d_reg[i] >> 7], 1);
        } else {
            d_reg[i] = -1;
        }
    }
    __syncthreads();

    for (int b = t; b < NB; b += 256) {
        int c = lh[b];
        lbase[b] = c ? atomicAdd(&bincursor[b], c) : 0;
    }
    __syncthreads();
    for (int b = t; b < NB; b += 256) lh[b] = 0;
    __syncthreads();

#pragma unroll
    for (int i = 0; i < 16; ++i) {
        int d = d_reg[i];
        if (d >= 0) {
            int bin = d >> 7;
            int r = atomicAdd(&lh[bin], 1);
            pairs[lbase[bin] + r] = make_int2(s_reg[i], d);
        }
    }
}

// ---------------- FILL2: per-bucket local CSR build ----------------

__global__ __launch_bounds__(256) void fill2_kernel(const int2* __restrict__ pairs,
                                                    const int* __restrict__ bincursor,
                                                    int* __restrict__ rowbeg,
                                                    int* __restrict__ rowend,
                                                    float* __restrict__ dinv,
                                                    int* __restrict__ csr_src) {
    __shared__ int deg[128];
    __shared__ int sc[128];
    __shared__ int cur[128];
    int t = threadIdx.x;
    int blk = blockIdx.x;
    int bs = blk * CAP;
    int be = bincursor[blk];

    if (t < 128) deg[t] = 0;
    __syncthreads();

    for (int p = bs + t; p < be; p += 256) atomicAdd(&deg[pairs[p].y & 127], 1);
    __syncthreads();

    if (t < 128) sc[t] = deg[t];
    __syncthreads();
#pragma unroll
    for (int off = 1; off < 128; off <<= 1) {
        int v = (t < 128 && t >= off) ? sc[t - off] : 0;
        __syncthreads();
        if (t < 128) sc[t] += v;
        __syncthreads();
    }

    if (t < 128) {
        int ex = sc[t] - deg[t];
        cur[t] = ex;
        int node = blk * 128 + t;
        if (node < N_NODES) {
            rowbeg[node] = bs + ex;
            rowend[node] = bs + sc[t];
            dinv[node] = rsqrtf((float)deg[t] + 1.0f);
        }
    }
    __syncthreads();

    for (int p = bs + t; p < be; p += 256) {
        int2 sd = pairs[p];
        int r = atomicAdd(&cur[sd.y & 127], 1);
        csr_src[bs + r] = sd.x;
    }
}

// ---------------- MFMA GEMM: Hs = bf16( (X @ W) * dinv[row] ) ----------------
// block = 4 waves x 16 rows = 64 rows, full N=128. B from global bf16 W^T (L1-hot).
// A frag: row=l&15, k=(l>>4)*8+j ; B frag: col=l&15 (W^T row), same k
// C/D: col=l&15, row=(l>>4)*4+reg

template <bool ABF>
__global__ __launch_bounds__(256) void mgemm_kernel(const void* __restrict__ Xv,
                                                    const uint* __restrict__ Wt,  // [128][64] uint
                                                    const float* __restrict__ dinv,
                                                    uint* __restrict__ Hs) {      // [M][64] uint
    int t = threadIdx.x;
    int wv = t >> 6;
    int l = t & 63;
    int col = l & 15;
    int g = l >> 4;
    int r0 = blockIdx.x * 64 + wv * 16;

    int ar = r0 + col;
    if (ar > N_NODES - 1) ar = N_NODES - 1;  // clamp (stores are guarded)

    bf16x8 a[4];
    if (ABF) {
        const uint4* Xr = (const uint4*)((const uint*)Xv + (size_t)ar * 64);
#pragma unroll
        for (int kk = 0; kk < 4; ++kk) a[kk] = __builtin_bit_cast(bf16x8, Xr[kk * 4 + g]);
    } else {
        const float4* Xr = (const float4*)((const float*)Xv + (size_t)ar * DIM);
#pragma unroll
        for (int kk = 0; kk < 4; ++kk) {
            float4 x0 = Xr[kk * 8 + g * 2];
            float4 x1 = Xr[kk * 8 + g * 2 + 1];
            uint4 p;
            p.x = f2bf(x0.x) | (f2bf(x0.y) << 16);
            p.y = f2bf(x0.z) | (f2bf(x0.w) << 16);
            p.z = f2bf(x1.x) | (f2bf(x1.y) << 16);
            p.w = f2bf(x1.z) | (f2bf(x1.w) << 16);
            a[kk] = __builtin_bit_cast(bf16x8, p);
        }
    }

    const uint4* Wr = (const uint4*)Wt;  // [128 rows][16 uint4]
    f32x4 acc[8];
#pragma unroll
    for (int n = 0; n < 8; ++n) acc[n] = (f32x4){0.f, 0.f, 0.f, 0.f};

#pragma unroll
    for (int n = 0; n < 8; ++n) {
        const uint4* wrow = Wr + (size_t)(n * 16 + col) * 16;
#pragma unroll
        for (int kk = 0; kk < 4; ++kk) {
            bf16x8 b = __builtin_bit_cast(bf16x8, wrow[kk * 4 + g]);
            acc[n] = __builtin_amdgcn_mfma_f32_16x16x32_bf16(a[kk], b, acc[n], 0, 0, 0);
        }
    }

#pragma unroll
    for (int j = 0; j < 4; ++j) {
        int row = r0 + g * 4 + j;
        if (row < N_NODES) {
            float di = dinv[row];
            ushort* hrow = (ushort*)(Hs + (size_t)row * 64);
#pragma unroll
            for (int n = 0; n < 8; ++n) {
                hrow[n * 16 + col] = (ushort)f2bf(acc[n][j] * di);
            }
        }
    }
}

// ---------------- aggregation (gather): one wave per dst node ----------------

template <bool RES, bool OBF>
__global__ __launch_bounds__(256) void agg_kernel(const int* __restrict__ rowbeg,
                                                  const int* __restrict__ rowend,
                                                  const int* __restrict__ csr_src,
                                                  const uint* __restrict__ Hs,
                                                  const float* __restrict__ dinv,
                                                  const float* __restrict__ b,
                                                  const float* __restrict__ resid,
                                                  void* __restrict__ outv) {
    int node = (int)((blockIdx.x * (size_t)blockDim.x + threadIdx.x) >> 6);
    int lane = threadIdx.x & 63;
    if (node >= N_NODES) return;

    int beg = rowbeg[node];
    int end = rowend[node];

    float2 self = bf2f2(Hs[(size_t)node * 64 + lane]);
    float ax = self.x, ay = self.y;

    int e = beg;
    for (; e + 3 < end; e += 4) {
        int s0 = csr_src[e], s1 = csr_src[e + 1], s2 = csr_src[e + 2], s3 = csr_src[e + 3];
        uint u0 = Hs[(size_t)s0 * 64 + lane];
        uint u1 = Hs[(size_t)s1 * 64 + lane];
        uint u2 = Hs[(size_t)s2 * 64 + lane];
        uint u3 = Hs[(size_t)s3 * 64 + lane];
        float2 v0 = bf2f2(u0), v1 = bf2f2(u1), v2 = bf2f2(u2), v3 = bf2f2(u3);
        ax += (v0.x + v1.x) + (v2.x + v3.x);
        ay += (v0.y + v1.y) + (v2.y + v3.y);
    }
    for (; e < end; ++e) {
        float2 v = bf2f2(Hs[(size_t)csr_src[e] * 64 + lane]);
        ax += v.x;
        ay += v.y;
    }

    float di = dinv[node];
    float2 bb = ((const float2*)b)[lane];
    float ox = ax * di + bb.x;
    float oy = ay * di + bb.y;
    if (OBF) {
        uint* o = (uint*)outv;
        o[(size_t)node * 64 + lane] = f2bf(fmaxf(ox, 0.f)) | (f2bf(fmaxf(oy, 0.f)) << 16);
    } else {
        if (RES) {
            float2 rv = ((const float2*)resid)[(size_t)node * 64 + lane];
            ox += rv.x;
            oy += rv.y;
        }
        ((float2*)outv)[(size_t)node * 64 + lane] =
            make_float2(fmaxf(ox, 0.f), fmaxf(oy, 0.f));
    }
}

// ---------------- launch ----------------

extern "C" void kernel_launch(void* const* d_in, const int* in_sizes, int n_in,
                              void* d_out, int out_size, void* d_ws, size_t ws_size,
                              hipStream_t stream) {
    const float* x = (const float*)d_in[0];
    const int* edge_index = (const int*)d_in[1];
    const float* W1 = (const float*)d_in[2];
    const float* b1 = (const float*)d_in[3];
    const float* W2 = (const float*)d_in[4];
    const float* b2 = (const float*)d_in[5];
    float* out = (float*)d_out;

    char* ws = (char*)d_ws;
    int*   bincursor = (int*)(ws + 0);              // 1.6 KB
    float* dinv      = (float*)(ws + (64 << 10));   // 200 KB
    int*   rowbeg    = (int*)(ws + (320 << 10));    // 200 KB
    int*   rowend    = (int*)(ws + (576 << 10));    // 200 KB
    int*   csr_src   = (int*)(ws + (1 << 20));      // 4.0 MB (padded)
    int2*  pairs     = (int2*)(ws + (6 << 20));     // 8.0 MB (padded)
    uint*  Hs        = (uint*)(ws + (15 << 20));    // 12.8 MB (bf16 packed)
    uint*  out1b     = (uint*)(ws + (28 << 20));    // 12.8 MB (bf16 packed)
    uint*  Wt1       = (uint*)(ws + (41 << 20));    // 32 KB
    uint*  Wt2       = (uint*)(ws + (41 << 20) + (64 << 10));  // 32 KB

    // ---- CSR build + W^T pre-pack
    initcur_kernel<<<2, 256, 0, stream>>>(bincursor);
    wt_kernel<<<64, 256, 0, stream>>>(W1, W2, Wt1, Wt2);
    bin_kernel<<<BIN_BLOCKS, 256, 0, stream>>>(edge_index, bincursor, pairs);
    fill2_kernel<<<NB, 256, 0, stream>>>(pairs, bincursor, rowbeg, rowend, dinv, csr_src);

    const int gemm_grid = (N_NODES + 63) / 64;
    const int agg_grid = (N_NODES * 64 + 255) / 256;

    // ---- conv1: Hs = bf16((x@W1)*dinv) ; out1b = bf16(relu(agg + b1))
    mgemm_kernel<false><<<gemm_grid, 256, 0, stream>>>(x, Wt1, dinv, Hs);
    agg_kernel<false, true><<<agg_grid, 256, 0, stream>>>(rowbeg, rowend, csr_src, Hs, dinv, b1,
                                                          nullptr, out1b);

    // ---- conv2: Hs = bf16((out1b@W2)*dinv) ; out = relu(agg + b2 + x) -> d_out
    mgemm_kernel<true><<<gemm_grid, 256, 0, stream>>>(out1b, Wt2, dinv, Hs);
    agg_kernel<true, false><<<agg_grid, 256, 0, stream>>>(rowbeg, rowend, csr_src, Hs, dinv, b2,
                                                          x, out);
}

// Round 7
// 146.409 us; speedup vs baseline: 11.0774x; 1.1146x over previous
//
#include <hip/hip_runtime.h>

#define N_NODES 50000
#define N_EDGES 800000
#define DIM 128
#define NB 391          // buckets of 128 nodes
#define CAP 2560        // padded capacity per bucket (mean 2048)
#define BIN_CHUNK 4096
#define BIN_BLOCKS 196

typedef unsigned int uint;
typedef unsigned short ushort;
typedef __attribute__((ext_vector_type(8))) __bf16 bf16x8;
typedef __attribute__((ext_vector_type(4))) float f32x4;

// ---- bf16 pack/unpack helpers (round-to-nearest-even) ----
__device__ __forceinline__ uint f2bf(float f) {
    uint u = __float_as_uint(f);
    return (u + 0x7FFFu + ((u >> 16) & 1u)) >> 16;
}
__device__ __forceinline__ float2 bf2f2(uint u) {
    return make_float2(__uint_as_float(u << 16), __uint_as_float(u & 0xFFFF0000u));
}

// ---------------- prep: W^T bf16 pre-pack + bucket cursor init ----------------

__global__ __launch_bounds__(256) void prep_kernel(const float* __restrict__ W1,
                                                   const float* __restrict__ W2,
                                                   uint* __restrict__ Wt1,
                                                   uint* __restrict__ Wt2,
                                                   int* __restrict__ bincursor) {
    int idx = blockIdx.x * 256 + threadIdx.x;  // 0..16895
    if (idx < 16384) {
        const float* W = (idx < 8192) ? W1 : W2;
        uint* Wt = (idx < 8192) ? Wt1 : Wt2;
        int i = idx & 8191;
        int n = i >> 6, k2 = i & 63;
        uint lo = f2bf(W[(2 * k2) * DIM + n]);
        uint hi = f2bf(W[(2 * k2 + 1) * DIM + n]);
        Wt[i] = lo | (hi << 16);
    } else {
        int b = idx - 16384;
        if (b < NB) bincursor[b] = b * CAP;
    }
}

// ---------------- BIN: scatter edges into 391 dst-buckets (packed uint) ----------------

__global__ __launch_bounds__(256) void bin_kernel(const int* __restrict__ ei,
                                                  int* __restrict__ bincursor,
                                                  uint* __restrict__ pairs) {
    __shared__ int lh[NB];
    __shared__ int lbase[NB];
    int t = threadIdx.x;
    int eb = blockIdx.x * BIN_CHUNK;

    for (int b = t; b < NB; b += 256) lh[b] = 0;
    __syncthreads();

    int s_reg[16], d_reg[16];
#pragma unroll
    for (int i = 0; i < 16; ++i) {
        int e = eb + i * 256 + t;
        if (e < N_EDGES) {
            s_reg[i] = ei[e];
            d_reg[i] = ei[N_EDGES + e];
            atomicAdd(&lh[d_reg[i] >> 7], 1);
        } else {
            d_reg[i] = -1;
        }
    }
    __syncthreads();

    for (int b = t; b < NB; b += 256) {
        int c = lh[b];
        lbase[b] = c ? atomicAdd(&bincursor[b], c) : 0;
    }
    __syncthreads();
    for (int b = t; b < NB; b += 256) lh[b] = 0;
    __syncthreads();

#pragma unroll
    for (int i = 0; i < 16; ++i) {
        int d = d_reg[i];
        if (d >= 0) {
            int bin = d >> 7;
            int r = atomicAdd(&lh[bin], 1);
            pairs[lbase[bin] + r] = ((uint)s_reg[i] << 7) | (uint)(d & 127);
        }
    }
}

// ---------------- FILL2: per-bucket local CSR build ----------------

__global__ __launch_bounds__(256) void fill2_kernel(const uint* __restrict__ pairs,
                                                    const int* __restrict__ bincursor,
                                                    int* __restrict__ rowbeg,
                                                    int* __restrict__ rowend,
                                                    float* __restrict__ dinv,
                                                    int* __restrict__ csr_src) {
    __shared__ int deg[128];
    __shared__ int sc[128];
    __shared__ int cur[128];
    int t = threadIdx.x;
    int blk = blockIdx.x;
    int bs = blk * CAP;
    int be = bincursor[blk];

    if (t < 128) deg[t] = 0;
    __syncthreads();

    for (int p = bs + t; p < be; p += 256) atomicAdd(&deg[pairs[p] & 127u], 1);
    __syncthreads();

    if (t < 128) sc[t] = deg[t];
    __syncthreads();
#pragma unroll
    for (int off = 1; off < 128; off <<= 1) {
        int v = (t < 128 && t >= off) ? sc[t - off] : 0;
        __syncthreads();
        if (t < 128) sc[t] += v;
        __syncthreads();
    }

    if (t < 128) {
        int ex = sc[t] - deg[t];
        cur[t] = ex;
        int node = blk * 128 + t;
        if (node < N_NODES) {
            rowbeg[node] = bs + ex;
            rowend[node] = bs + sc[t];
            dinv[node] = rsqrtf((float)deg[t] + 1.0f);
        }
    }
    __syncthreads();

    for (int p = bs + t; p < be; p += 256) {
        uint sd = pairs[p];
        int r = atomicAdd(&cur[sd & 127u], 1);
        csr_src[bs + r] = (int)(sd >> 7);
    }
}

// ---------------- MFMA GEMM: Hs = bf16( (X @ W) * dinv[row] ) ----------------

template <bool ABF>
__global__ __launch_bounds__(256) void mgemm_kernel(const void* __restrict__ Xv,
                                                    const uint* __restrict__ Wt,  // [128][64] uint
                                                    const float* __restrict__ dinv,
                                                    uint* __restrict__ Hs) {      // [M][64] uint
    int t = threadIdx.x;
    int wv = t >> 6;
    int l = t & 63;
    int col = l & 15;
    int g = l >> 4;
    int r0 = blockIdx.x * 64 + wv * 16;

    int ar = r0 + col;
    if (ar > N_NODES - 1) ar = N_NODES - 1;  // clamp (stores are guarded)

    bf16x8 a[4];
    if (ABF) {
        const uint4* Xr = (const uint4*)((const uint*)Xv + (size_t)ar * 64);
#pragma unroll
        for (int kk = 0; kk < 4; ++kk) a[kk] = __builtin_bit_cast(bf16x8, Xr[kk * 4 + g]);
    } else {
        const float4* Xr = (const float4*)((const float*)Xv + (size_t)ar * DIM);
#pragma unroll
        for (int kk = 0; kk < 4; ++kk) {
            float4 x0 = Xr[kk * 8 + g * 2];
            float4 x1 = Xr[kk * 8 + g * 2 + 1];
            uint4 p;
            p.x = f2bf(x0.x) | (f2bf(x0.y) << 16);
            p.y = f2bf(x0.z) | (f2bf(x0.w) << 16);
            p.z = f2bf(x1.x) | (f2bf(x1.y) << 16);
            p.w = f2bf(x1.z) | (f2bf(x1.w) << 16);
            a[kk] = __builtin_bit_cast(bf16x8, p);
        }
    }

    const uint4* Wr = (const uint4*)Wt;  // [128 rows][16 uint4]
    f32x4 acc[8];
#pragma unroll
    for (int n = 0; n < 8; ++n) acc[n] = (f32x4){0.f, 0.f, 0.f, 0.f};

#pragma unroll
    for (int n = 0; n < 8; ++n) {
        const uint4* wrow = Wr + (size_t)(n * 16 + col) * 16;
#pragma unroll
        for (int kk = 0; kk < 4; ++kk) {
            bf16x8 b = __builtin_bit_cast(bf16x8, wrow[kk * 4 + g]);
            acc[n] = __builtin_amdgcn_mfma_f32_16x16x32_bf16(a[kk], b, acc[n], 0, 0, 0);
        }
    }

#pragma unroll
    for (int j = 0; j < 4; ++j) {
        int row = r0 + g * 4 + j;
        if (row < N_NODES) {
            float di = dinv[row];
            ushort* hrow = (ushort*)(Hs + (size_t)row * 64);
#pragma unroll
            for (int n = 0; n < 8; ++n) {
                hrow[n * 16 + col] = (ushort)f2bf(acc[n][j] * di);
            }
        }
    }
}

// ---------------- aggregation v2: 4 nodes/wave, 16 lanes/node, uint4/lane ----------------

template <bool RES, bool OBF>
__global__ __launch_bounds__(256) void agg_kernel(const int* __restrict__ rowbeg,
                                                  const int* __restrict__ rowend,
                                                  const int* __restrict__ csr_src,
                                                  const uint* __restrict__ Hs,
                                                  const float* __restrict__ dinv,
                                                  const float* __restrict__ b,
                                                  const float* __restrict__ resid,
                                                  void* __restrict__ outv) {
    int wave = (int)((blockIdx.x * (size_t)blockDim.x + threadIdx.x) >> 6);
    int lane = threadIdx.x & 63;
    int grp = lane >> 4;
    int li = lane & 15;
    int node = wave * 4 + grp;  // 50000 = 12500 waves * 4, exact

    int beg = rowbeg[node];
    int end = rowend[node];

    const uint4* H4 = (const uint4*)Hs;
    float a0, a1, a2, a3, a4, a5, a6, a7;
    {
        uint4 su = H4[(size_t)node * 16 + li];
        float2 v0 = bf2f2(su.x), v1 = bf2f2(su.y), v2 = bf2f2(su.z), v3 = bf2f2(su.w);
        a0 = v0.x; a1 = v0.y; a2 = v1.x; a3 = v1.y;
        a4 = v2.x; a5 = v2.y; a6 = v3.x; a7 = v3.y;
    }

#define ADD8(u)                                                                   \
    {                                                                             \
        float2 v0 = bf2f2(u.x), v1 = bf2f2(u.y), v2 = bf2f2(u.z), v3 = bf2f2(u.w);\
        a0 += v0.x; a1 += v0.y; a2 += v1.x; a3 += v1.y;                           \
        a4 += v2.x; a5 += v2.y; a6 += v3.x; a7 += v3.y;                           \
    }

    int e = beg;
    for (; e + 1 < end; e += 2) {
        int s0 = csr_src[e];
        int s1 = csr_src[e + 1];
        uint4 u0 = H4[(size_t)s0 * 16 + li];
        uint4 u1 = H4[(size_t)s1 * 16 + li];
        ADD8(u0);
        ADD8(u1);
    }
    if (e < end) {
        int s = csr_src[e];
        uint4 u = H4[(size_t)s * 16 + li];
        ADD8(u);
    }
#undef ADD8

    float di = dinv[node];
    const float4* B4 = (const float4*)b;
    float4 bb0 = B4[li * 2], bb1 = B4[li * 2 + 1];
    float r0 = a0 * di + bb0.x, r1 = a1 * di + bb0.y;
    float r2 = a2 * di + bb0.z, r3 = a3 * di + bb0.w;
    float r4 = a4 * di + bb1.x, r5 = a5 * di + bb1.y;
    float r6 = a6 * di + bb1.z, r7 = a7 * di + bb1.w;

    if (OBF) {
        uint4 o;
        o.x = f2bf(fmaxf(r0, 0.f)) | (f2bf(fmaxf(r1, 0.f)) << 16);
        o.y = f2bf(fmaxf(r2, 0.f)) | (f2bf(fmaxf(r3, 0.f)) << 16);
        o.z = f2bf(fmaxf(r4, 0.f)) | (f2bf(fmaxf(r5, 0.f)) << 16);
        o.w = f2bf(fmaxf(r6, 0.f)) | (f2bf(fmaxf(r7, 0.f)) << 16);
        ((uint4*)outv)[(size_t)node * 16 + li] = o;
    } else {
        if (RES) {
            const float4* R4 = (const float4*)(resid + (size_t)node * DIM);
            float4 x0 = R4[li * 2], x1 = R4[li * 2 + 1];
            r0 += x0.x; r1 += x0.y; r2 += x0.z; r3 += x0.w;
            r4 += x1.x; r5 += x1.y; r6 += x1.z; r7 += x1.w;
        }
        float4* O4 = (float4*)((float*)outv + (size_t)node * DIM);
        O4[li * 2] = make_float4(fmaxf(r0, 0.f), fmaxf(r1, 0.f), fmaxf(r2, 0.f), fmaxf(r3, 0.f));
        O4[li * 2 + 1] = make_float4(fmaxf(r4, 0.f), fmaxf(r5, 0.f), fmaxf(r6, 0.f), fmaxf(r7, 0.f));
    }
}

// ---------------- launch ----------------

extern "C" void kernel_launch(void* const* d_in, const int* in_sizes, int n_in,
                              void* d_out, int out_size, void* d_ws, size_t ws_size,
                              hipStream_t stream) {
    const float* x = (const float*)d_in[0];
    const int* edge_index = (const int*)d_in[1];
    const float* W1 = (const float*)d_in[2];
    const float* b1 = (const float*)d_in[3];
    const float* W2 = (const float*)d_in[4];
    const float* b2 = (const float*)d_in[5];
    float* out = (float*)d_out;

    char* ws = (char*)d_ws;
    int*   bincursor = (int*)(ws + 0);              // 1.6 KB
    float* dinv      = (float*)(ws + (64 << 10));   // 200 KB
    int*   rowbeg    = (int*)(ws + (320 << 10));    // 200 KB
    int*   rowend    = (int*)(ws + (576 << 10));    // 200 KB
    int*   csr_src   = (int*)(ws + (1 << 20));      // 4.0 MB (padded)
    uint*  pairs     = (uint*)(ws + (6 << 20));     // 4.0 MB (packed, padded)
    uint*  Hs        = (uint*)(ws + (11 << 20));    // 12.8 MB (bf16 packed)
    uint*  out1b     = (uint*)(ws + (24 << 20));    // 12.8 MB (bf16 packed)
    uint*  Wt1       = (uint*)(ws + (37 << 20));    // 32 KB
    uint*  Wt2       = (uint*)(ws + (37 << 20) + (64 << 10));  // 32 KB

    // ---- prep (W^T pack + cursor init) + CSR build
    prep_kernel<<<66, 256, 0, stream>>>(W1, W2, Wt1, Wt2, bincursor);
    bin_kernel<<<BIN_BLOCKS, 256, 0, stream>>>(edge_index, bincursor, pairs);
    fill2_kernel<<<NB, 256, 0, stream>>>(pairs, bincursor, rowbeg, rowend, dinv, csr_src);

    const int gemm_grid = (N_NODES + 63) / 64;
    const int agg_grid = (N_NODES / 4 + 3) / 4;  // 12500 waves / 4 waves-per-block = 3125

    // ---- conv1: Hs = bf16((x@W1)*dinv) ; out1b = bf16(relu(agg + b1))
    mgemm_kernel<false><<<gemm_grid, 256, 0, stream>>>(x, Wt1, dinv, Hs);
    agg_kernel<false, true><<<agg_grid, 256, 0, stream>>>(rowbeg, rowend, csr_src, Hs, dinv, b1,
                                                          nullptr, out1b);

    // ---- conv2: Hs = bf16((out1b@W2)*dinv) ; out = relu(agg + b2 + x) -> d_out
    mgemm_kernel<true><<<gemm_grid, 256, 0, stream>>>(out1b, Wt2, dinv, Hs);
    agg_kernel<true, false><<<agg_grid, 256, 0, stream>>>(rowbeg, rowend, csr_src, Hs, dinv, b2,
                                                          x, out);
}